// Round 1
// baseline (412.681 us; speedup 1.0000x reference)
//
#include <hip/hip_runtime.h>
#include <math.h>

namespace {
constexpr int   kB        = 8192;
constexpr int   kBlock    = 256;
constexpr int   kVec      = 4;
constexpr int   kIters    = kB / (kBlock * kVec);   // 8 float4 loads per thread
constexpr float kMargin   = 0.1f;
constexpr float kThresh   = 0.5f;
constexpr float kScalePos = 2.0f;
constexpr float kScaleNeg = 40.0f;
constexpr float kEps      = 1e-5f;
}

// One block per row. Row (32 KiB) lives in registers (32 floats/thread),
// label-equality cached as a 32-bit mask per thread, so sim_mat is read
// from HBM exactly once. Kernel is HBM-read-bound: 256 MiB / ~6.3 TB/s.
__global__ __launch_bounds__(kBlock) void ms_loss_kernel(
    const float* __restrict__ sim,
    const int*   __restrict__ labels,
    float*       __restrict__ out)
{
  const int row  = blockIdx.x;
  const int tid  = threadIdx.x;
  const int wave = tid >> 6;
  const int lane = tid & 63;

  const int my_label = labels[row];                    // block-uniform (s_load)
  const float* __restrict__ srow = sim + (size_t)row * kB;

  float4       vals[kIters];
  unsigned int same_mask = 0;
  float min_pos =  INFINITY;   // hardest positive (min over same & sim<1-eps)
  float max_neg = -INFINITY;   // hardest negative (max over !same)

  // ---- Pass 1: coalesced float4 load, masks + hardest-pair partials ----
  #pragma unroll
  for (int k = 0; k < kIters; ++k) {
    const int j = k * (kBlock * kVec) + tid * kVec;
    const float4 v = *reinterpret_cast<const float4*>(srow + j);
    const int4   l = *reinterpret_cast<const int4*>(labels + j);
    vals[k] = v;
    const float xs[4] = {v.x, v.y, v.z, v.w};
    const int   ls[4] = {l.x, l.y, l.z, l.w};
    #pragma unroll
    for (int c = 0; c < 4; ++c) {
      if (ls[c] == my_label) {
        same_mask |= 1u << (k * 4 + c);
        if (xs[c] < 1.0f - kEps) min_pos = fminf(min_pos, xs[c]);
      } else {
        max_neg = fmaxf(max_neg, xs[c]);
      }
    }
  }

  // ---- Block reduce min_pos / max_neg ----
  #pragma unroll
  for (int off = 32; off > 0; off >>= 1) {
    min_pos = fminf(min_pos, __shfl_xor(min_pos, off, 64));
    max_neg = fmaxf(max_neg, __shfl_xor(max_neg, off, 64));
  }
  __shared__ float s_min[kBlock / 64];
  __shared__ float s_max[kBlock / 64];
  if (lane == 0) { s_min[wave] = min_pos; s_max[wave] = max_neg; }
  __syncthreads();
  min_pos = fminf(fminf(s_min[0], s_min[1]), fminf(s_min[2], s_min[3]));
  max_neg = fmaxf(fmaxf(s_max[0], s_max[1]), fmaxf(s_max[2], s_max[3]));

  // ---- Pass 2 (from registers): mined exp-sums ----
  // any(sel_pos) <=> pos_sum > 0 since exp(..) > 0 and min value
  // exp(-60) ~ 9e-27 stays well above fp32 underflow.
  float pos_sum = 0.0f, neg_sum = 0.0f;
  #pragma unroll
  for (int k = 0; k < kIters; ++k) {
    const float4 v = vals[k];
    const float xs[4] = {v.x, v.y, v.z, v.w};
    #pragma unroll
    for (int c = 0; c < 4; ++c) {
      const float x = xs[c];
      if ((same_mask >> (k * 4 + c)) & 1u) {
        if (x < 1.0f - kEps && (x - kMargin < max_neg))
          pos_sum += expf(-kScalePos * (x - kThresh));
      } else {
        if (x + kMargin > min_pos)
          neg_sum += expf(kScaleNeg * (x - kThresh));
      }
    }
  }

  // ---- Block reduce sums, one atomic per row ----
  #pragma unroll
  for (int off = 32; off > 0; off >>= 1) {
    pos_sum += __shfl_xor(pos_sum, off, 64);
    neg_sum += __shfl_xor(neg_sum, off, 64);
  }
  __shared__ float s_pos[kBlock / 64];
  __shared__ float s_neg[kBlock / 64];
  if (lane == 0) { s_pos[wave] = pos_sum; s_neg[wave] = neg_sum; }
  __syncthreads();
  if (tid == 0) {
    pos_sum = (s_pos[0] + s_pos[1]) + (s_pos[2] + s_pos[3]);
    neg_sum = (s_neg[0] + s_neg[1]) + (s_neg[2] + s_neg[3]);
    if (pos_sum > 0.0f && neg_sum > 0.0f) {
      const float loss = log1pf(pos_sum) * (1.0f / kScalePos)
                       + log1pf(neg_sum) * (1.0f / kScaleNeg);
      atomicAdd(out, loss * (1.0f / (float)kB));
    }
  }
}

extern "C" void kernel_launch(void* const* d_in, const int* in_sizes, int n_in,
                              void* d_out, int out_size, void* d_ws, size_t ws_size,
                              hipStream_t stream) {
  const float* sim    = (const float*)d_in[0];
  const int*   labels = (const int*)d_in[1];
  float*       out    = (float*)d_out;

  // d_out is re-poisoned to 0xAA before every timed launch — zero it here.
  hipMemsetAsync(d_out, 0, sizeof(float) * (size_t)out_size, stream);
  ms_loss_kernel<<<dim3(kB), dim3(kBlock), 0, stream>>>(sim, labels, out);
}

// Round 2
// 377.618 us; speedup vs baseline: 1.0929x; 1.0929x over previous
//
#include <hip/hip_runtime.h>
#include <math.h>

namespace {
constexpr int   kB        = 8192;
constexpr int   kBlock    = 256;
constexpr int   kVec      = 4;
constexpr int   kIters    = kB / (kBlock * kVec);   // 8 float4 loads per thread
constexpr float kMargin   = 0.1f;
constexpr float kThresh   = 0.5f;
constexpr float kScalePos = 2.0f;
constexpr float kScaleNeg = 40.0f;
constexpr float kEps      = 1e-5f;
}

// One block per row; the 32 KiB row lives in REGISTERS (32 floats/thread).
// __launch_bounds__(256,4): 4 waves/EU -> 128-VGPR budget, so the compiler
// keeps v[8] (32 VGPRs) resident and batches all 8 loads for full MLP.
// (R1 failure mode: default occupancy target gave 28 VGPRs -> serialized
// load-use chains, 851 GB/s. This trades occupancy 72%->50% for 8 loads
// in flight per wave.)
__global__ __launch_bounds__(kBlock, 4) void ms_loss_kernel(
    const float* __restrict__ sim,
    const int*   __restrict__ labels,
    float*       __restrict__ out)
{
  const int row  = blockIdx.x;
  const int tid  = threadIdx.x;
  const int wave = tid >> 6;
  const int lane = tid & 63;

  const int my_label = labels[row];                 // block-uniform
  const float* __restrict__ srow = sim + (size_t)row * kB;

  // ---- Issue ALL sim loads up front (8 dwordx4 outstanding per wave) ----
  float4 v[kIters];
  #pragma unroll
  for (int k = 0; k < kIters; ++k) {
    v[k] = *reinterpret_cast<const float4*>(srow + k * (kBlock * kVec) + tid * kVec);
  }

  // ---- Labels (same 32 KiB for every block -> L1/L2-hot) -> bitmask ----
  unsigned int same_mask = 0;
  #pragma unroll
  for (int k = 0; k < kIters; ++k) {
    const int4 l = *reinterpret_cast<const int4*>(labels + k * (kBlock * kVec) + tid * kVec);
    same_mask |= (unsigned)(l.x == my_label) << (k * 4 + 0);
    same_mask |= (unsigned)(l.y == my_label) << (k * 4 + 1);
    same_mask |= (unsigned)(l.z == my_label) << (k * 4 + 2);
    same_mask |= (unsigned)(l.w == my_label) << (k * 4 + 3);
  }

  // ---- Pass 1 (registers): hardest positive / hardest negative, branchless ----
  float min_pos =  INFINITY;   // min over same & sim < 1-eps
  float max_neg = -INFINITY;   // max over !same
  #pragma unroll
  for (int k = 0; k < kIters; ++k) {
    const float xs[4] = {v[k].x, v[k].y, v[k].z, v[k].w};
    #pragma unroll
    for (int c = 0; c < 4; ++c) {
      const bool  same = (same_mask >> (k * 4 + c)) & 1u;
      const float x = xs[c];
      const float p = (same && x < 1.0f - kEps) ? x : INFINITY;
      const float n = same ? -INFINITY : x;
      min_pos = fminf(min_pos, p);
      max_neg = fmaxf(max_neg, n);
    }
  }

  // ---- Block reduce + broadcast min_pos / max_neg ----
  #pragma unroll
  for (int off = 32; off > 0; off >>= 1) {
    min_pos = fminf(min_pos, __shfl_xor(min_pos, off, 64));
    max_neg = fmaxf(max_neg, __shfl_xor(max_neg, off, 64));
  }
  __shared__ float s_min[kBlock / 64];
  __shared__ float s_max[kBlock / 64];
  if (lane == 0) { s_min[wave] = min_pos; s_max[wave] = max_neg; }
  __syncthreads();
  min_pos = fminf(fminf(s_min[0], s_min[1]), fminf(s_min[2], s_min[3]));
  max_neg = fmaxf(fmaxf(s_max[0], s_max[1]), fmaxf(s_max[2], s_max[3]));

  // ---- Pass 2 (registers): mined exp-sums, ONE v_exp_f32 per element ----
  // any(sel_pos) <=> pos_sum > 0: exp args are in [-60, 20] -> 2^-86.6 min,
  // still a normal fp32, never flushes to 0.
  float pos_sum = 0.0f, neg_sum = 0.0f;
  #pragma unroll
  for (int k = 0; k < kIters; ++k) {
    const float xs[4] = {v[k].x, v[k].y, v[k].z, v[k].w};
    #pragma unroll
    for (int c = 0; c < 4; ++c) {
      const bool  same = (same_mask >> (k * 4 + c)) & 1u;
      const float x = xs[c];
      const float a = same ? -kScalePos : kScaleNeg;
      const float e = __expf(a * (x - kThresh));
      const bool selp = same && (x < 1.0f - kEps) && (x - kMargin < max_neg);
      const bool seln = (!same) && (x + kMargin > min_pos);
      pos_sum += selp ? e : 0.0f;
      neg_sum += seln ? e : 0.0f;
    }
  }

  // ---- Block reduce sums, one atomic per row ----
  #pragma unroll
  for (int off = 32; off > 0; off >>= 1) {
    pos_sum += __shfl_xor(pos_sum, off, 64);
    neg_sum += __shfl_xor(neg_sum, off, 64);
  }
  __shared__ float s_pos[kBlock / 64];
  __shared__ float s_neg[kBlock / 64];
  if (lane == 0) { s_pos[wave] = pos_sum; s_neg[wave] = neg_sum; }
  __syncthreads();
  if (tid == 0) {
    pos_sum = (s_pos[0] + s_pos[1]) + (s_pos[2] + s_pos[3]);
    neg_sum = (s_neg[0] + s_neg[1]) + (s_neg[2] + s_neg[3]);
    if (pos_sum > 0.0f && neg_sum > 0.0f) {
      const float loss = log1pf(pos_sum) * (1.0f / kScalePos)
                       + log1pf(neg_sum) * (1.0f / kScaleNeg);
      atomicAdd(out, loss * (1.0f / (float)kB));
    }
  }
}

extern "C" void kernel_launch(void* const* d_in, const int* in_sizes, int n_in,
                              void* d_out, int out_size, void* d_ws, size_t ws_size,
                              hipStream_t stream) {
  const float* sim    = (const float*)d_in[0];
  const int*   labels = (const int*)d_in[1];
  float*       out    = (float*)d_out;

  // d_out is re-poisoned to 0xAA before every timed launch — zero it here.
  hipMemsetAsync(d_out, 0, sizeof(float) * (size_t)out_size, stream);
  ms_loss_kernel<<<dim3(kB), dim3(kBlock), 0, stream>>>(sim, labels, out);
}

// Round 3
// 371.168 us; speedup vs baseline: 1.1118x; 1.0174x over previous
//
#include <hip/hip_runtime.h>
#include <math.h>

namespace {
constexpr int   kB        = 8192;
constexpr int   kBlock    = 256;
constexpr int   kVec      = 4;
constexpr int   kChunks   = kB / (kBlock * kVec);   // 8 float4 per thread per row
constexpr int   kRows     = 8;                      // rows per block
constexpr int   kGrid     = kB / kRows;             // 1024 blocks = exactly 4/CU
constexpr float kMargin   = 0.1f;
constexpr float kThresh   = 0.5f;
constexpr float kScalePos = 2.0f;
constexpr float kScaleNeg = 40.0f;
constexpr float kEps      = 1e-5f;
}

// R3: software-pipelined row processing. R2's failure mode: 4 phase-locked
// blocks/CU -> memory pipe idle during the ~4-5K-cycle compute phase of every
// block (effective ~2 TB/s). Here each block owns 8 contiguous rows and
// prefetches row r+1's 8 dwordx4 into a ping-pong register buffer while
// computing row r, so loads stay in flight continuously. Labels are read ONCE
// per block and collapsed into 8 per-row 32-bit masks in the prologue, so the
// steady-state loop's only memory ops are the sim prefetch (clean vmcnt).
__global__ __launch_bounds__(kBlock, 4) void ms_loss_kernel(
    const float* __restrict__ sim,
    const int*   __restrict__ labels,
    float*       __restrict__ out)
{
  const int tid      = threadIdx.x;
  const int wave     = tid >> 6;
  const int lane     = tid & 63;
  const int base_row = blockIdx.x * kRows;

  // ---- Prologue A: labels -> per-row same-bitmasks (labels read once) ----
  int4 lab[kChunks];
  #pragma unroll
  for (int k = 0; k < kChunks; ++k)
    lab[k] = *reinterpret_cast<const int4*>(labels + k * (kBlock * kVec) + tid * kVec);

  unsigned int mask[kRows];
  #pragma unroll
  for (int r = 0; r < kRows; ++r) {
    const int ml = labels[base_row + r];             // block-uniform -> s_load
    unsigned int m = 0;
    #pragma unroll
    for (int k = 0; k < kChunks; ++k) {
      m |= (unsigned)(lab[k].x == ml) << (k * 4 + 0);
      m |= (unsigned)(lab[k].y == ml) << (k * 4 + 1);
      m |= (unsigned)(lab[k].z == ml) << (k * 4 + 2);
      m |= (unsigned)(lab[k].w == ml) << (k * 4 + 3);
    }
    mask[r] = m;
  }
  // lab[] dead here -> registers recycled for buf[].

  // ---- Prologue B: issue row 0's sim loads ----
  float4 buf[2][kChunks];
  {
    const float* __restrict__ s0 = sim + (size_t)base_row * kB;
    #pragma unroll
    for (int k = 0; k < kChunks; ++k)
      buf[0][k] = *reinterpret_cast<const float4*>(s0 + k * (kBlock * kVec) + tid * kVec);
  }

  __shared__ float s_min[kBlock / 64];
  __shared__ float s_max[kBlock / 64];
  __shared__ float s_pos[kBlock / 64];
  __shared__ float s_neg[kBlock / 64];

  float block_loss = 0.0f;

  #pragma unroll
  for (int r = 0; r < kRows; ++r) {
    // -- Prefetch row r+1 while row r computes (the pipeline) --
    if (r + 1 < kRows) {
      const float* __restrict__ sn = sim + (size_t)(base_row + r + 1) * kB;
      #pragma unroll
      for (int k = 0; k < kChunks; ++k)
        buf[(r + 1) & 1][k] =
            *reinterpret_cast<const float4*>(sn + k * (kBlock * kVec) + tid * kVec);
    }

    const unsigned int m = mask[r];

    // -- Pass 1 (registers): hardest positive / hardest negative --
    float min_pos =  INFINITY;
    float max_neg = -INFINITY;
    #pragma unroll
    for (int k = 0; k < kChunks; ++k) {
      const float4 v = buf[r & 1][k];
      const float xs[4] = {v.x, v.y, v.z, v.w};
      #pragma unroll
      for (int c = 0; c < 4; ++c) {
        const bool  same = (m >> (k * 4 + c)) & 1u;
        const float x = xs[c];
        min_pos = fminf(min_pos, (same && x < 1.0f - kEps) ? x : INFINITY);
        max_neg = fmaxf(max_neg, same ? -INFINITY : x);
      }
    }
    #pragma unroll
    for (int off = 32; off > 0; off >>= 1) {
      min_pos = fminf(min_pos, __shfl_xor(min_pos, off, 64));
      max_neg = fmaxf(max_neg, __shfl_xor(max_neg, off, 64));
    }
    if (lane == 0) { s_min[wave] = min_pos; s_max[wave] = max_neg; }
    __syncthreads();
    min_pos = fminf(fminf(s_min[0], s_min[1]), fminf(s_min[2], s_min[3]));
    max_neg = fmaxf(fmaxf(s_max[0], s_max[1]), fmaxf(s_max[2], s_max[3]));

    // -- Pass 2 (registers): mined exp-sums, one v_exp_f32 per element --
    // exp args in [-60, 20]: never underflows, so pos_sum>0 <=> any(sel_pos).
    float pos_sum = 0.0f, neg_sum = 0.0f;
    #pragma unroll
    for (int k = 0; k < kChunks; ++k) {
      const float4 v = buf[r & 1][k];
      const float xs[4] = {v.x, v.y, v.z, v.w};
      #pragma unroll
      for (int c = 0; c < 4; ++c) {
        const bool  same = (m >> (k * 4 + c)) & 1u;
        const float x = xs[c];
        const float a = same ? -kScalePos : kScaleNeg;
        const float e = __expf(a * (x - kThresh));
        const bool selp = same && (x < 1.0f - kEps) && (x - kMargin < max_neg);
        const bool seln = (!same) && (x + kMargin > min_pos);
        pos_sum += selp ? e : 0.0f;
        neg_sum += seln ? e : 0.0f;
      }
    }
    #pragma unroll
    for (int off = 32; off > 0; off >>= 1) {
      pos_sum += __shfl_xor(pos_sum, off, 64);
      neg_sum += __shfl_xor(neg_sum, off, 64);
    }
    if (lane == 0) { s_pos[wave] = pos_sum; s_neg[wave] = neg_sum; }
    __syncthreads();
    if (tid == 0) {
      pos_sum = (s_pos[0] + s_pos[1]) + (s_pos[2] + s_pos[3]);
      neg_sum = (s_neg[0] + s_neg[1]) + (s_neg[2] + s_neg[3]);
      if (pos_sum > 0.0f && neg_sum > 0.0f) {
        block_loss += log1pf(pos_sum) * (1.0f / kScalePos)
                    + log1pf(neg_sum) * (1.0f / kScaleNeg);
      }
    }
  }

  if (tid == 0 && block_loss != 0.0f) {
    atomicAdd(out, block_loss * (1.0f / (float)kB));
  }
}

extern "C" void kernel_launch(void* const* d_in, const int* in_sizes, int n_in,
                              void* d_out, int out_size, void* d_ws, size_t ws_size,
                              hipStream_t stream) {
  const float* sim    = (const float*)d_in[0];
  const int*   labels = (const int*)d_in[1];
  float*       out    = (float*)d_out;

  // d_out is re-poisoned to 0xAA before every timed launch — zero it here.
  hipMemsetAsync(d_out, 0, sizeof(float) * (size_t)out_size, stream);
  ms_loss_kernel<<<dim3(kGrid), dim3(kBlock), 0, stream>>>(sim, labels, out);
}